// Round 3
// baseline (931.289 us; speedup 1.0000x reference)
//
#include <hip/hip_runtime.h>

#define T_STEPS 336
#define NWG_LAUNCH 256   // full machine; co-resident by capacity (128 VGPR -> 2 blocks/CU
                         // => cap 512 blocks). Winner team self-selects via XCC_ID.

typedef unsigned long long u64;
typedef unsigned int u32;

// Device-global scratch. First launch: .bss zeros = tag0|h0=0 (valid t=0 state).
// Later launches: winner-team owners re-tag their slots for t=0 (both parities,
// both transports); stale terminal tags (336/335) never match targets (0/1),
// and within a launch slot tags are monotone 0..336.
__device__ float g_h[337 * 512];      // h_1..h_336 (head reads t>=81)
__device__ float g_blw[256 * 512];    // sampled BayesianLinear weight
__device__ u64   g_fast[2][512];      // parity bufs: XCD-L2 path (sc0) — winner team only
__device__ u64   g_slow[2][512];      // parity bufs: MALL path (agent) — proven fallback
__device__ u32   g_bar;               // monotone grid-barrier counter (NEVER reset:
                                      // each barrier instance occupies an aligned
                                      // 256-window, so no cross-launch cleanup)
__device__ u32   g_cnt[8];            // per-XCD registration (reset each launch by bid 0)

__device__ __forceinline__ float softplus_f(float x) {
  return (x > 20.f) ? x : log1pf(__expf(x));
}
__device__ __forceinline__ float sigmoid_f(float x) {
  return 1.f / (1.f + __expf(-x));
}
__device__ __forceinline__ float tanh_f(float x) {
  x = fminf(fmaxf(x, -15.f), 15.f);
  float e = __expf(-2.f * x);
  return (1.f - e) / (1.f + e);
}

// sc0 = L1-bypass, L2-coherent: CU-to-CU visibility through the shared
// per-XCD L2 (~120-200cy) instead of agent/MALL (~500-900cy). Only valid
// between CUs on the SAME XCD — which the winner team guarantees by
// construction (XCC_ID-verified membership).
__device__ __forceinline__ u64 ld_l2(const u64* p) {
  u64 v;
  asm volatile("global_load_dwordx2 %0, %1, off sc0\n\t"
               "s_waitcnt vmcnt(0)"
               : "=&v"(v) : "v"(p) : "memory");
  return v;
}
__device__ __forceinline__ void st_l2(u64* p, u64 v) {
  asm volatile("global_store_dwordx2 %0, %1, off sc0"
               :: "v"(p), "v"(v) : "memory");
}

// Reset-free grid barrier: one arrival per block (tid 0). Monotone counter;
// barrier instance k occupies exactly the aligned window [256k, 256(k+1))
// because no block can arrive at instance k+1 before instance k fully
// releases. acq_rel add + acquire spin pairs release/acquire so writes
// program-order-before an arrival are visible after the barrier.
__device__ __forceinline__ void grid_arrive_wait() {
  u32 old = __hip_atomic_fetch_add(&g_bar, 1u, __ATOMIC_ACQ_REL, __HIP_MEMORY_SCOPE_AGENT);
  u32 target = (old & ~255u) + 256u;
  for (;;) {
    u32 v = __hip_atomic_load(&g_bar, __ATOMIC_ACQUIRE, __HIP_MEMORY_SCOPE_AGENT);
    if ((int)(v - target) >= 0) break;
  }
}

// ---------------- persistent LSTM recurrence ----------------
// SELF-ORGANIZING placement (round-2 lesson: bid&7 does NOT co-locate on an
// XCD — the fast path never fired, per-step rose to 2.45us = 8-poll cadence
// on the slow path). Now: 256 blocks launch; each reads its PHYSICAL XCD via
// s_getreg(HW_REG_XCC_ID) [measured: learn_hip m09] and registers. Pigeonhole
// (256 blocks / 8 XCDs) guarantees some XCD hosts >=32 blocks; the lowest
// such XCD's first 32 registrants become the team (roles 0..31), everyone
// else exits. The team is PROVABLY single-XCD -> sc0 transport through that
// XCD's shared L2 is coherent.
// DUAL-PUBLISH retained as insurance (producer tail writes both g_fast sc0
// and g_slow agent — the proven deadlock-free structure; consumers poll fast
// every iter, probe slow every 8th). If XCC_ID semantics surprise, we degrade
// to round-2 speed with correct results; no deadlock is possible.
// WG r owns h-indices [16r,16r+16). Thread (seg=tid>>6, cl=tid&63):
// col=(cl>>4)*512+16r+(cl&15), rows [64seg,64seg+64), 64 sampled Whh weights
// in registers (FULL unroll or w[] demotes to scratch). Wave seg polls exactly
// the 64 h-slots its dot consumes -> no poll->dot barrier; part[] parity-
// double-buffered -> single __syncthreads per step.
__global__ __launch_bounds__(512) void lstm_kernel(
    const float* __restrict__ x, const float* __restrict__ drop_x,
    const float* __restrict__ wih_mu, const float* __restrict__ wih_rho, const float* __restrict__ eps_wih,
    const float* __restrict__ b_mu, const float* __restrict__ b_rho, const float* __restrict__ eps_b,
    const float* __restrict__ whh_mu, const float* __restrict__ whh_rho, const float* __restrict__ eps_whh,
    const float* __restrict__ blw_mu, const float* __restrict__ blw_rho, const float* __restrict__ eps_blw)
{
  const int bid = blockIdx.x;
  const int tid = threadIdx.x;      // 0..511

  // ---- team formation (one-time, ~10-30us incl. two grid barriers) ----
  __shared__ int s_role;
  if (tid == 0) {
    if (bid == 0) {
      #pragma unroll
      for (int j = 0; j < 8; ++j)
        __hip_atomic_store(&g_cnt[j], 0u, __ATOMIC_RELAXED, __HIP_MEMORY_SCOPE_AGENT);
    }
    grid_arrive_wait();             // barrier 1: resets visible to all registrants
    u32 xcd;
    asm volatile("s_getreg_b32 %0, hwreg(HW_REG_XCC_ID)" : "=s"(xcd));
    xcd &= 7u;
    u32 slot = __hip_atomic_fetch_add(&g_cnt[xcd], 1u,
                                      __ATOMIC_ACQ_REL, __HIP_MEMORY_SCOPE_AGENT);
    grid_arrive_wait();             // barrier 2: all registrations final
    int winner = -1;
    #pragma unroll
    for (int j = 0; j < 8; ++j) {
      u32 c = __hip_atomic_load(&g_cnt[j], __ATOMIC_RELAXED, __HIP_MEMORY_SCOPE_AGENT);
      if (winner < 0 && c >= 32u) winner = j;
    }
    s_role = ((int)xcd == winner && slot < 32u) ? (int)slot : -1;
  }
  __syncthreads();
  const int role = s_role;
  if (role < 0) return;             // 224 blocks exit; 32 single-XCD blocks persist

  const int r = role;               // 0..31: WG role within the winner team
  const int cl = tid & 63;
  const int seg = tid >> 6;         // 0..7
  const int gate = cl >> 4, kl = cl & 15;
  const int col = gate * 512 + r * 16 + kl;
  const int row0 = seg * 64;

  // Re-tag my own 16 slots for t=0 (both parities, both transports).
  // Owners-only -> no cross-WG write races; consumers' t=0 polls wait for
  // these (or hit first-launch .bss zeros, which are the valid t=0 state).
  if (tid < 16) {
    const int idx = r * 16 + tid;
    st_l2(&g_fast[0][idx], 0ULL);
    st_l2(&g_fast[1][idx], 0ULL);
    __hip_atomic_store(&g_slow[0][idx], 0ULL, __ATOMIC_RELAXED, __HIP_MEMORY_SCOPE_AGENT);
    __hip_atomic_store(&g_slow[1][idx], 0ULL, __ATOMIC_RELAXED, __HIP_MEMORY_SCOPE_AGENT);
  }

  __shared__ float xd[336 * 16];    // x*drop_x for batch 255
  __shared__ float hs[512];         // fp32 h copy (wave-local segments)
  __shared__ float part[2][8][64];  // parity-double-buffered partials

  // One-time: sample BLW (consumed by head after this kernel completes).
  // Winner team covers all of it: roles 0..31 x 512 threads x 8 elems = 128K.
  {
    const int e0 = (r * 512 + tid) * 8;
    #pragma unroll
    for (int q = 0; q < 8; ++q) {
      const int e = e0 + q;
      g_blw[e] = blw_mu[e] + softplus_f(blw_rho[e]) * eps_blw[e];
    }
  }

  for (int e = tid; e < 5376; e += 512) {
    const int src = 255 * 5376 + e;   // batch-255 slice is contiguous
    xd[e] = x[src] * drop_x[src];
  }

  // 64 sampled Whh weights into registers.
  float w[64];
  #pragma unroll
  for (int j = 0; j < 64; ++j) {
    const int idx = (row0 + j) * 2048 + col;
    w[j] = whh_mu[idx] + softplus_f(whh_rho[idx]) * eps_whh[idx];
  }

  // Wave 0: Wih column + bias for on-the-fly xg.
  float wih[16];
  float bias = 0.f;
  if (tid < 64) {
    bias = b_mu[col] + softplus_f(b_rho[col]) * eps_b[col];
    #pragma unroll
    for (int i = 0; i < 16; ++i) {
      const int idx = i * 2048 + col;
      wih[i] = wih_mu[idx] + softplus_f(wih_rho[idx]) * eps_wih[idx];
    }
  }
  __syncthreads();                  // xd staged

  auto xg_at = [&](int t) -> float {
    const float4* xr = (const float4*)(xd + t * 16);
    float4 x0 = xr[0], x1 = xr[1], x2 = xr[2], x3 = xr[3];
    float s0 = fmaf(x0.x, wih[0], bias);
    s0 = fmaf(x0.y, wih[1], s0); s0 = fmaf(x0.z, wih[2], s0); s0 = fmaf(x0.w, wih[3], s0);
    float s1 = x1.x * wih[4];
    s1 = fmaf(x1.y, wih[5], s1); s1 = fmaf(x1.z, wih[6], s1); s1 = fmaf(x1.w, wih[7], s1);
    float s2 = x2.x * wih[8];
    s2 = fmaf(x2.y, wih[9], s2); s2 = fmaf(x2.z, wih[10], s2); s2 = fmaf(x2.w, wih[11], s2);
    float s3 = x3.x * wih[12];
    s3 = fmaf(x3.y, wih[13], s3); s3 = fmaf(x3.z, wih[14], s3); s3 = fmaf(x3.w, wih[15], s3);
    return (s0 + s1) + (s2 + s3);
  };

  float c = 0.f;                    // cell state (wave-0 lanes 0..15)
  float xgv = (tid < 64) ? xg_at(0) : 0.f;

  for (int t = 0; t < T_STEPS; ++t) {
    const int p = t & 1;

    // Poll my slot: fast path through this XCD's L2 (team is single-XCD by
    // construction, so this is the expected hit); slow probe every 8th iter
    // is pure insurance.
    {
      const u64* fsl = &g_fast[p][tid];
      u64 v;
      unsigned it = 0;
      for (;;) {
        v = ld_l2(fsl);
        if ((unsigned)(v >> 32) == (unsigned)t) break;
        if ((++it & 7u) == 0u) {
          v = __hip_atomic_load(&g_slow[p][tid], __ATOMIC_RELAXED,
                                __HIP_MEMORY_SCOPE_AGENT);
          if ((unsigned)(v >> 32) == (unsigned)t) break;
        }
        if (it > (1u << 22)) break;   // anti-hang insurance (never fires: slow path proven)
      }
      hs[tid] = __uint_as_float((unsigned)v);
    }
    // No barrier: wave seg's dot reads hs[row0..row0+64) = its own lanes' data.

    float a0 = 0.f, a1 = 0.f, a2 = 0.f, a3 = 0.f;
    const float4* hv = (const float4*)(hs + row0);
    #pragma unroll
    for (int jj = 0; jj < 16; ++jj) {
      float4 h4 = hv[jj];
      a0 = fmaf(h4.x, w[4 * jj],     a0);
      a1 = fmaf(h4.y, w[4 * jj + 1], a1);
      a2 = fmaf(h4.z, w[4 * jj + 2], a2);
      a3 = fmaf(h4.w, w[4 * jj + 3], a3);
    }
    part[p][seg][cl] = (a0 + a1) + (a2 + a3);
    __syncthreads();   // single rendezvous per step (skew-safe via parity bufs)

    if (tid < 64) {
      float g = xgv
              + ((part[p][0][tid] + part[p][1][tid]) + (part[p][2][tid] + part[p][3][tid]))
              + ((part[p][4][tid] + part[p][5][tid]) + (part[p][6][tid] + part[p][7][tid]));
      // Parallel activation on all 64 lanes (one exp chain each):
      // gates i,f,o -> sigmoid; gate g -> tanh = 2*sigmoid(2x)-1 (clamped).
      const bool is_g = (gate == 2);
      float xin = is_g ? 2.f * fminf(fmaxf(g, -15.f), 15.f) : g;
      float s = sigmoid_f(xin);
      float act = is_g ? 2.f * s - 1.f : s;
      float vi = __shfl(act, kl);
      float vf = __shfl(act, kl + 16);
      float vg = __shfl(act, kl + 32);
      float vo = __shfl(act, kl + 48);
      if (tid < 16) {
        c = vf * c + vi * vg;
        float h = vo * tanh_f(c);
        const int idx = r * 16 + tid;
        u64 pv = (((u64)(unsigned)(t + 1)) << 32) | (u64)__float_as_uint(h);
        st_l2(&g_fast[(t + 1) & 1][idx], pv);          // fast publish (this XCD's L2)
        __hip_atomic_store(&g_slow[(t + 1) & 1][idx], pv,
                           __ATOMIC_RELAXED, __HIP_MEMORY_SCOPE_AGENT);  // proven MALL publish
        g_h[(t + 1) * 512 + idx] = h;                  // for head (kernel-end flush)
      }
      if (t + 1 < T_STEPS) xgv = xg_at(t + 1);         // off critical path
    }
  }
}

// ---------------- head ----------------
// block j: last[j] = g_h[81+j]  (reshape(T,B,H)[-1] => h_{t=80+j} of batch 255)
// y[l] = relu(last*drop_h[j] . BLW[l] + BLb[l]) * drop_l[j,l]; out = y @ lin_w^T.
// BLb sampled inline per block (256 redundant softplus -- free).
__global__ __launch_bounds__(256) void head_kernel(
    const float* __restrict__ drop_h, const float* __restrict__ drop_l,
    const float* __restrict__ blb_mu, const float* __restrict__ blb_rho,
    const float* __restrict__ eps_blb,
    const float* __restrict__ lin_w, float* __restrict__ out)
{
  const int j = blockIdx.x, tid = threadIdx.x;
  __shared__ float hd[512];
  __shared__ float y[256];

  for (int k = tid; k < 512; k += 256)
    hd[k] = g_h[(81 + j) * 512 + k] * drop_h[j * 512 + k];
  __syncthreads();

  {
    const int l = tid;
    float acc = blb_mu[l] + softplus_f(blb_rho[l]) * eps_blb[l];
    const float* wrow = g_blw + l * 512;
    #pragma unroll 8
    for (int k = 0; k < 512; ++k) acc = fmaf(hd[k], wrow[k], acc);
    acc = fmaxf(acc, 0.f);
    y[l] = acc * drop_l[j * 256 + l];
  }
  __syncthreads();

  if (tid < 10) {
    float acc = 0.f;
    const float* lrow = lin_w + tid * 256;
    #pragma unroll 8
    for (int l = 0; l < 256; ++l) acc = fmaf(y[l], lrow[l], acc);
    out[j * 10 + tid] = acc;
  }
}

// ---------------- launch (2 dispatches) ----------------
extern "C" void kernel_launch(void* const* d_in, const int* in_sizes, int n_in,
                              void* d_out, int out_size, void* d_ws, size_t ws_size,
                              hipStream_t stream) {
  const float* x        = (const float*)d_in[0];
  const float* drop_x   = (const float*)d_in[1];
  const float* drop_h   = (const float*)d_in[2];
  const float* drop_l   = (const float*)d_in[3];
  const float* wih_mu   = (const float*)d_in[4];
  const float* wih_rho  = (const float*)d_in[5];
  const float* eps_wih  = (const float*)d_in[6];
  const float* whh_mu   = (const float*)d_in[7];
  const float* whh_rho  = (const float*)d_in[8];
  const float* eps_whh  = (const float*)d_in[9];
  const float* b_mu     = (const float*)d_in[10];
  const float* b_rho    = (const float*)d_in[11];
  const float* eps_b    = (const float*)d_in[12];
  const float* blw_mu   = (const float*)d_in[13];
  const float* blw_rho  = (const float*)d_in[14];
  const float* eps_blw  = (const float*)d_in[15];
  const float* blb_mu   = (const float*)d_in[16];
  const float* blb_rho  = (const float*)d_in[17];
  const float* eps_blb  = (const float*)d_in[18];
  const float* lin_w    = (const float*)d_in[19];

  lstm_kernel<<<NWG_LAUNCH, 512, 0, stream>>>(x, drop_x,
                                              wih_mu, wih_rho, eps_wih,
                                              b_mu, b_rho, eps_b,
                                              whh_mu, whh_rho, eps_whh,
                                              blw_mu, blw_rho, eps_blw);

  head_kernel<<<256, 256, 0, stream>>>(drop_h, drop_l,
                                       blb_mu, blb_rho, eps_blb,
                                       lin_w, (float*)d_out);
}

// Round 4
// 790.947 us; speedup vs baseline: 1.1774x; 1.1774x over previous
//
#include <hip/hip_runtime.h>

#define T_STEPS 336
#define NWG 32

typedef unsigned long long u64;

// Device-global scratch. g_hh slot tags are re-initialized by their OWNING WG
// at lstm startup each call (first call: .bss zeros = tag0|h0=0, exactly the
// valid t=0 state; later calls: stale tags 336/335 never match targets 0/1).
__device__ float g_h[337 * 512];      // h_1..h_336 (head reads t>=81)
__device__ float g_blw[256 * 512];    // sampled BayesianLinear weight
__device__ u64   g_hh[2][512];        // parity buffers: (tag<<32)|h_bits

__device__ __forceinline__ float softplus_f(float x) {
  return (x > 20.f) ? x : log1pf(__expf(x));
}
__device__ __forceinline__ float sigmoid_f(float x) {
  return 1.f / (1.f + __expf(-x));
}
__device__ __forceinline__ float tanh_f(float x) {
  x = fminf(fmaxf(x, -15.f), 15.f);
  float e = __expf(-2.f * x);
  return (1.f - e) / (1.f + e);
}

// ---------------- persistent LSTM recurrence ----------------
// 32 WGs x 512 threads; the PROVEN round-0 structure (single agent publish,
// poll g_hh) with ONE change: 3-deep software-pipelined polling.
//   Rationale: same-address polls serialize at cadence = load latency L
//   (~0.4us), so discovery ~1.5L and the step barrier eats up to ~L of
//   inter-wave discovery skew. vmcnt retires in issue order (T4 basis), so
//   keeping 3 polls in flight and waiting vmcnt(2) gives check cadence L/3:
//   discovery ~L+L/6 and ~3x less skew. Loads use sc1 (best-evidence agent
//   bit); every 4th rotation falls back to a proven __hip_atomic_load probe,
//   so a wrong sc1 scope degrades to ~round-2 speed with CORRECT results
//   (same acyclic publish->poll graph as the 619us baseline; no deadlock).
// Rounds 1-3 lesson: sc0-only ops never transport cross-CU (rounds 2/3
// identical regardless of XCD placement); post-barrier republish deadlocks.
// WG r owns h-indices [16r,16r+16). Thread (seg=tid>>6, cl=tid&63):
// col=(cl>>4)*512+16r+(cl&15), rows [64seg,64seg+64), 64 sampled Whh weights
// in registers (FULL unroll or w[] demotes to scratch). Wave seg polls exactly
// the 64 h-slots its dot consumes -> no poll->dot barrier; part[] parity-
// double-buffered -> single __syncthreads per step.
__global__ __launch_bounds__(512) void lstm_kernel(
    const float* __restrict__ x, const float* __restrict__ drop_x,
    const float* __restrict__ wih_mu, const float* __restrict__ wih_rho, const float* __restrict__ eps_wih,
    const float* __restrict__ b_mu, const float* __restrict__ b_rho, const float* __restrict__ eps_b,
    const float* __restrict__ whh_mu, const float* __restrict__ whh_rho, const float* __restrict__ eps_whh,
    const float* __restrict__ blw_mu, const float* __restrict__ blw_rho, const float* __restrict__ eps_blw)
{
  const int r = blockIdx.x;         // 0..31
  const int tid = threadIdx.x;      // 0..511
  const int cl = tid & 63;
  const int seg = tid >> 6;         // 0..7
  const int gate = cl >> 4, kl = cl & 15;
  const int col = gate * 512 + r * 16 + kl;
  const int row0 = seg * 64;

  // FIRST: re-tag my own 16 slots for t=0 (both parities). Owners-only ->
  // no cross-WG write races; consumers' t=0 polls wait for these stores.
  if (tid < 16) {
    const int idx = r * 16 + tid;
    __hip_atomic_store(&g_hh[0][idx], 0ULL, __ATOMIC_RELAXED, __HIP_MEMORY_SCOPE_AGENT);
    __hip_atomic_store(&g_hh[1][idx], 0ULL, __ATOMIC_RELAXED, __HIP_MEMORY_SCOPE_AGENT);
  }

  __shared__ float xd[336 * 16];    // x*drop_x for batch 255
  __shared__ float hs[512];         // fp32 h copy (wave-local segments)
  __shared__ float part[2][8][64];  // parity-double-buffered partials

  // One-time: sample BLW (consumed by head after this kernel completes).
  {
    const int e0 = (r * 512 + tid) * 8;
    #pragma unroll
    for (int q = 0; q < 8; ++q) {
      const int e = e0 + q;
      g_blw[e] = blw_mu[e] + softplus_f(blw_rho[e]) * eps_blw[e];
    }
  }

  for (int e = tid; e < 5376; e += 512) {
    const int src = 255 * 5376 + e;   // batch-255 slice is contiguous
    xd[e] = x[src] * drop_x[src];
  }

  // 64 sampled Whh weights into registers.
  float w[64];
  #pragma unroll
  for (int j = 0; j < 64; ++j) {
    const int idx = (row0 + j) * 2048 + col;
    w[j] = whh_mu[idx] + softplus_f(whh_rho[idx]) * eps_whh[idx];
  }

  // Wave 0: Wih column + bias for on-the-fly xg.
  float wih[16];
  float bias = 0.f;
  if (tid < 64) {
    bias = b_mu[col] + softplus_f(b_rho[col]) * eps_b[col];
    #pragma unroll
    for (int i = 0; i < 16; ++i) {
      const int idx = i * 2048 + col;
      wih[i] = wih_mu[idx] + softplus_f(wih_rho[idx]) * eps_wih[idx];
    }
  }
  __syncthreads();                  // xd staged

  auto xg_at = [&](int t) -> float {
    const float4* xr = (const float4*)(xd + t * 16);
    float4 x0 = xr[0], x1 = xr[1], x2 = xr[2], x3 = xr[3];
    float s0 = fmaf(x0.x, wih[0], bias);
    s0 = fmaf(x0.y, wih[1], s0); s0 = fmaf(x0.z, wih[2], s0); s0 = fmaf(x0.w, wih[3], s0);
    float s1 = x1.x * wih[4];
    s1 = fmaf(x1.y, wih[5], s1); s1 = fmaf(x1.z, wih[6], s1); s1 = fmaf(x1.w, wih[7], s1);
    float s2 = x2.x * wih[8];
    s2 = fmaf(x2.y, wih[9], s2); s2 = fmaf(x2.z, wih[10], s2); s2 = fmaf(x2.w, wih[11], s2);
    float s3 = x3.x * wih[12];
    s3 = fmaf(x3.y, wih[13], s3); s3 = fmaf(x3.z, wih[14], s3); s3 = fmaf(x3.w, wih[15], s3);
    return (s0 + s1) + (s2 + s3);
  };

  float c = 0.f;                    // cell state (wave-0 lanes 0..15)
  float xgv = (tid < 64) ? xg_at(0) : 0.f;

  for (int t = 0; t < T_STEPS; ++t) {
    const int p = t & 1;

    // 3-deep pipelined poll. vmcnt retires in issue order, so vmcnt(2)
    // guarantees the OLDEST copy has landed; check cadence = L/3 instead
    // of L. Older publish stores (2, lanes<16 only) retire first under
    // vmcnt(2) — that wait coincides with value-visibility time, so it
    // costs nothing extra. Every 4th rotation: proven agent probe.
    u64 v0, v1, v2, hv = 0;
    {
      const u64* slot = &g_hh[p][tid];
      bool done = false;
      unsigned it = 0;
      asm volatile("global_load_dwordx2 %0, %1, off sc1" : "=v"(v0) : "v"(slot) : "memory");
      asm volatile("global_load_dwordx2 %0, %1, off sc1" : "=v"(v1) : "v"(slot) : "memory");
      asm volatile("global_load_dwordx2 %0, %1, off sc1" : "=v"(v2) : "v"(slot) : "memory");
      for (;;) {
        asm volatile("s_waitcnt vmcnt(2)" ::: "memory");
        if (!done && (unsigned)(v0 >> 32) == (unsigned)t) { hv = v0; done = true; }
        if (__all((int)done)) break;
        asm volatile("global_load_dwordx2 %0, %1, off sc1" : "=v"(v0) : "v"(slot) : "memory");
        asm volatile("s_waitcnt vmcnt(2)" ::: "memory");
        if (!done && (unsigned)(v1 >> 32) == (unsigned)t) { hv = v1; done = true; }
        if (__all((int)done)) break;
        asm volatile("global_load_dwordx2 %0, %1, off sc1" : "=v"(v1) : "v"(slot) : "memory");
        asm volatile("s_waitcnt vmcnt(2)" ::: "memory");
        if (!done && (unsigned)(v2 >> 32) == (unsigned)t) { hv = v2; done = true; }
        if (__all((int)done)) break;
        asm volatile("global_load_dwordx2 %0, %1, off sc1" : "=v"(v2) : "v"(slot) : "memory");
        if ((++it & 3u) == 0u) {     // insurance: proven agent transport
          u64 s = __hip_atomic_load(slot, __ATOMIC_RELAXED, __HIP_MEMORY_SCOPE_AGENT);
          if (!done && (unsigned)(s >> 32) == (unsigned)t) { hv = s; done = true; }
          if (__all((int)done)) break;
        }
        if (it > (1u << 20)) break;  // anti-hang insurance (never fires: probe path proven)
      }
      hs[tid] = __uint_as_float((unsigned)hv);
    }
    // No barrier: wave seg's dot reads hs[row0..row0+64) = its own lanes' data.

    float a0 = 0.f, a1 = 0.f, a2 = 0.f, a3 = 0.f;
    const float4* hv4 = (const float4*)(hs + row0);
    #pragma unroll
    for (int jj = 0; jj < 16; ++jj) {
      float4 h4 = hv4[jj];
      a0 = fmaf(h4.x, w[4 * jj],     a0);
      a1 = fmaf(h4.y, w[4 * jj + 1], a1);
      a2 = fmaf(h4.z, w[4 * jj + 2], a2);
      a3 = fmaf(h4.w, w[4 * jj + 3], a3);
    }
    part[p][seg][cl] = (a0 + a1) + (a2 + a3);
    // Drain residual in-flight polls (<=2) here, hidden under the dot we just
    // did; liveness pin keeps their dest pairs allocated until the drain.
    asm volatile("s_waitcnt vmcnt(0)" ::: "memory");
    asm volatile("" :: "v"(v0), "v"(v1), "v"(v2));
    __syncthreads();   // single rendezvous per step (skew-safe via parity bufs)

    if (tid < 64) {
      float g = xgv
              + ((part[p][0][tid] + part[p][1][tid]) + (part[p][2][tid] + part[p][3][tid]))
              + ((part[p][4][tid] + part[p][5][tid]) + (part[p][6][tid] + part[p][7][tid]));
      // Parallel activation on all 64 lanes (one exp chain each):
      // gates i,f,o -> sigmoid; gate g -> tanh = 2*sigmoid(2x)-1 (clamped).
      const bool is_g = (gate == 2);
      float xin = is_g ? 2.f * fminf(fmaxf(g, -15.f), 15.f) : g;
      float s = sigmoid_f(xin);
      float act = is_g ? 2.f * s - 1.f : s;
      float vi = __shfl(act, kl);
      float vf = __shfl(act, kl + 16);
      float vg = __shfl(act, kl + 32);
      float vo = __shfl(act, kl + 48);
      if (tid < 16) {
        c = vf * c + vi * vg;
        float h = vo * tanh_f(c);
        const int idx = r * 16 + tid;
        u64 pv = (((u64)(unsigned)(t + 1)) << 32) | (u64)__float_as_uint(h);
        __hip_atomic_store(&g_hh[(t + 1) & 1][idx], pv,
                           __ATOMIC_RELAXED, __HIP_MEMORY_SCOPE_AGENT);   // publish first
        g_h[(t + 1) * 512 + idx] = h;                  // for head (kernel-end flush)
      }
      if (t + 1 < T_STEPS) xgv = xg_at(t + 1);         // off critical path
    }
  }
}

// ---------------- head ----------------
// block j: last[j] = g_h[81+j]  (reshape(T,B,H)[-1] => h_{t=80+j} of batch 255)
// y[l] = relu(last*drop_h[j] . BLW[l] + BLb[l]) * drop_l[j,l]; out = y @ lin_w^T.
// BLb sampled inline per block (256 redundant softplus -- free).
__global__ __launch_bounds__(256) void head_kernel(
    const float* __restrict__ drop_h, const float* __restrict__ drop_l,
    const float* __restrict__ blb_mu, const float* __restrict__ blb_rho,
    const float* __restrict__ eps_blb,
    const float* __restrict__ lin_w, float* __restrict__ out)
{
  const int j = blockIdx.x, tid = threadIdx.x;
  __shared__ float hd[512];
  __shared__ float y[256];

  for (int k = tid; k < 512; k += 256)
    hd[k] = g_h[(81 + j) * 512 + k] * drop_h[j * 512 + k];
  __syncthreads();

  {
    const int l = tid;
    float acc = blb_mu[l] + softplus_f(blb_rho[l]) * eps_blb[l];
    const float* wrow = g_blw + l * 512;
    #pragma unroll 8
    for (int k = 0; k < 512; ++k) acc = fmaf(hd[k], wrow[k], acc);
    acc = fmaxf(acc, 0.f);
    y[l] = acc * drop_l[j * 256 + l];
  }
  __syncthreads();

  if (tid < 10) {
    float acc = 0.f;
    const float* lrow = lin_w + tid * 256;
    #pragma unroll 8
    for (int l = 0; l < 256; ++l) acc = fmaf(y[l], lrow[l], acc);
    out[j * 10 + tid] = acc;
  }
}

// ---------------- launch (2 dispatches) ----------------
extern "C" void kernel_launch(void* const* d_in, const int* in_sizes, int n_in,
                              void* d_out, int out_size, void* d_ws, size_t ws_size,
                              hipStream_t stream) {
  const float* x        = (const float*)d_in[0];
  const float* drop_x   = (const float*)d_in[1];
  const float* drop_h   = (const float*)d_in[2];
  const float* drop_l   = (const float*)d_in[3];
  const float* wih_mu   = (const float*)d_in[4];
  const float* wih_rho  = (const float*)d_in[5];
  const float* eps_wih  = (const float*)d_in[6];
  const float* whh_mu   = (const float*)d_in[7];
  const float* whh_rho  = (const float*)d_in[8];
  const float* eps_whh  = (const float*)d_in[9];
  const float* b_mu     = (const float*)d_in[10];
  const float* b_rho    = (const float*)d_in[11];
  const float* eps_b    = (const float*)d_in[12];
  const float* blw_mu   = (const float*)d_in[13];
  const float* blw_rho  = (const float*)d_in[14];
  const float* eps_blw  = (const float*)d_in[15];
  const float* blb_mu   = (const float*)d_in[16];
  const float* blb_rho  = (const float*)d_in[17];
  const float* eps_blb  = (const float*)d_in[18];
  const float* lin_w    = (const float*)d_in[19];

  lstm_kernel<<<NWG, 512, 0, stream>>>(x, drop_x,
                                       wih_mu, wih_rho, eps_wih,
                                       b_mu, b_rho, eps_b,
                                       whh_mu, whh_rho, eps_whh,
                                       blw_mu, blw_rho, eps_blw);

  head_kernel<<<256, 256, 0, stream>>>(drop_h, drop_l,
                                       blb_mu, blb_rho, eps_blb,
                                       lin_w, (float*)d_out);
}

// Round 5
// 687.134 us; speedup vs baseline: 1.3553x; 1.1511x over previous
//
#include <hip/hip_runtime.h>

#define T_STEPS 336
#define NWG 32
#define NREP 4

typedef unsigned long long u64;

// Device-global scratch. Replica slot tags are re-initialized by their OWNING
// WG at lstm startup each call (first call: .bss zeros = tag0|h0=0, exactly
// the valid t=0 state; later calls: stale tags 336/335 never match 0/1).
__device__ float g_h[337 * 512];      // h_1..h_336 (head reads t>=81)
__device__ float g_blw[256 * 512];    // sampled BayesianLinear weight
// 4 replicas x 2 parities x 8 wave-windows x 64 slots: (tag<<32)|h_bits.
// Replication divides per-line poll contention by 4: consumer WG r polls
// replica r&3, so each 512B window is polled by 8 waves instead of 32.
__device__ u64   g_rep[NREP][2][8][64];

__device__ __forceinline__ float softplus_f(float x) {
  return (x > 20.f) ? x : log1pf(__expf(x));
}
__device__ __forceinline__ float sigmoid_f(float x) {
  return 1.f / (1.f + __expf(-x));
}
__device__ __forceinline__ float tanh_f(float x) {
  x = fminf(fmaxf(x, -15.f), 15.f);
  float e = __expf(-2.f * x);
  return (1.f - e) / (1.f + e);
}

// ---------------- persistent LSTM recurrence ----------------
// 32 WGs x 512 threads; the PROVEN round-0 structure (relaxed agent-atomic
// publish, plain atomic-load polling — the only transport with zero outliers)
// with ONE isolated change: 4-way REPLICATED publish to divide MALL line
// contention. Round-4 lesson: the per-step wall is poll-queue CONTENTION at
// the MALL (3x poll rate -> +0.34us/step typical + one 32ms outlier), so we
// reduce per-line reader count (32 -> 8 waves/window), not poll latency.
// Rounds 1-3 lesson: sc0/sc1 cache-bit games never transport reliably;
// post-barrier republish deadlocks. Neither is used here.
// WG r owns h-indices [16r,16r+16). Thread (seg=tid>>6, cl=tid&63):
// col=(cl>>4)*512+16r+(cl&15), rows [64seg,64seg+64), 64 sampled Whh weights
// in registers (FULL unroll or w[] demotes to scratch). Wave seg polls exactly
// the 64 h-slots its dot consumes -> no poll->dot barrier; part[] parity-
// double-buffered -> single __syncthreads per step.
__global__ __launch_bounds__(512) void lstm_kernel(
    const float* __restrict__ x, const float* __restrict__ drop_x,
    const float* __restrict__ wih_mu, const float* __restrict__ wih_rho, const float* __restrict__ eps_wih,
    const float* __restrict__ b_mu, const float* __restrict__ b_rho, const float* __restrict__ eps_b,
    const float* __restrict__ whh_mu, const float* __restrict__ whh_rho, const float* __restrict__ eps_whh,
    const float* __restrict__ blw_mu, const float* __restrict__ blw_rho, const float* __restrict__ eps_blw)
{
  const int r = blockIdx.x;         // 0..31
  const int tid = threadIdx.x;      // 0..511
  const int cl = tid & 63;
  const int seg = tid >> 6;         // 0..7
  const int gate = cl >> 4, kl = cl & 15;
  const int col = gate * 512 + r * 16 + kl;
  const int row0 = seg * 64;
  const int rep = r & (NREP - 1);   // my WG's poll replica

  // FIRST: re-tag my own 16 slots for t=0 (all replicas, both parities).
  // Owners-only -> no cross-WG write races; consumers' t=0 polls wait for
  // these stores (or hit first-launch .bss zeros = valid t=0 state).
  if (tid < 16) {
    const int idx = r * 16 + tid;
    const int sw = idx >> 6, sc = idx & 63;
    #pragma unroll
    for (int q = 0; q < NREP; ++q) {
      __hip_atomic_store(&g_rep[q][0][sw][sc], 0ULL, __ATOMIC_RELAXED, __HIP_MEMORY_SCOPE_AGENT);
      __hip_atomic_store(&g_rep[q][1][sw][sc], 0ULL, __ATOMIC_RELAXED, __HIP_MEMORY_SCOPE_AGENT);
    }
  }

  __shared__ float xd[336 * 16];    // x*drop_x for batch 255
  __shared__ float hs[512];         // fp32 h copy (wave-local segments)
  __shared__ float part[2][8][64];  // parity-double-buffered partials

  // One-time: sample BLW (consumed by head after this kernel completes).
  {
    const int e0 = (r * 512 + tid) * 8;
    #pragma unroll
    for (int q = 0; q < 8; ++q) {
      const int e = e0 + q;
      g_blw[e] = blw_mu[e] + softplus_f(blw_rho[e]) * eps_blw[e];
    }
  }

  for (int e = tid; e < 5376; e += 512) {
    const int src = 255 * 5376 + e;   // batch-255 slice is contiguous
    xd[e] = x[src] * drop_x[src];
  }

  // 64 sampled Whh weights into registers.
  float w[64];
  #pragma unroll
  for (int j = 0; j < 64; ++j) {
    const int idx = (row0 + j) * 2048 + col;
    w[j] = whh_mu[idx] + softplus_f(whh_rho[idx]) * eps_whh[idx];
  }

  // Wave 0: Wih column + bias for on-the-fly xg.
  float wih[16];
  float bias = 0.f;
  if (tid < 64) {
    bias = b_mu[col] + softplus_f(b_rho[col]) * eps_b[col];
    #pragma unroll
    for (int i = 0; i < 16; ++i) {
      const int idx = i * 2048 + col;
      wih[i] = wih_mu[idx] + softplus_f(wih_rho[idx]) * eps_wih[idx];
    }
  }
  __syncthreads();                  // xd staged

  auto xg_at = [&](int t) -> float {
    const float4* xr = (const float4*)(xd + t * 16);
    float4 x0 = xr[0], x1 = xr[1], x2 = xr[2], x3 = xr[3];
    float s0 = fmaf(x0.x, wih[0], bias);
    s0 = fmaf(x0.y, wih[1], s0); s0 = fmaf(x0.z, wih[2], s0); s0 = fmaf(x0.w, wih[3], s0);
    float s1 = x1.x * wih[4];
    s1 = fmaf(x1.y, wih[5], s1); s1 = fmaf(x1.z, wih[6], s1); s1 = fmaf(x1.w, wih[7], s1);
    float s2 = x2.x * wih[8];
    s2 = fmaf(x2.y, wih[9], s2); s2 = fmaf(x2.z, wih[10], s2); s2 = fmaf(x2.w, wih[11], s2);
    float s3 = x3.x * wih[12];
    s3 = fmaf(x3.y, wih[13], s3); s3 = fmaf(x3.z, wih[14], s3); s3 = fmaf(x3.w, wih[15], s3);
    return (s0 + s1) + (s2 + s3);
  };

  float c = 0.f;                    // cell state (wave-0 lanes 0..15)
  float xgv = (tid < 64) ? xg_at(0) : 0.f;

  for (int t = 0; t < T_STEPS; ++t) {
    const int p = t & 1;

    // Poll my replica slot (proven transport, baseline rate; tag t carries
    // the h value). Only 8 waves poll this 512B window -> short MALL queues.
    {
      const u64* slot = &g_rep[rep][p][seg][cl];
      u64 v;
      int it = 0;
      for (;;) {
        v = __hip_atomic_load(slot, __ATOMIC_RELAXED, __HIP_MEMORY_SCOPE_AGENT);
        if ((unsigned)(v >> 32) == (unsigned)t) break;
        if (++it > (1 << 22)) break;   // anti-hang insurance (never fires in practice)
      }
      hs[tid] = __uint_as_float((unsigned)v);
    }
    // No barrier: wave seg's dot reads hs[row0..row0+64) = its own lanes' data.

    float a0 = 0.f, a1 = 0.f, a2 = 0.f, a3 = 0.f;
    const float4* hv = (const float4*)(hs + row0);
    #pragma unroll
    for (int jj = 0; jj < 16; ++jj) {
      float4 h4 = hv[jj];
      a0 = fmaf(h4.x, w[4 * jj],     a0);
      a1 = fmaf(h4.y, w[4 * jj + 1], a1);
      a2 = fmaf(h4.z, w[4 * jj + 2], a2);
      a3 = fmaf(h4.w, w[4 * jj + 3], a3);
    }
    part[p][seg][cl] = (a0 + a1) + (a2 + a3);
    __syncthreads();   // single rendezvous per step (skew-safe via parity bufs)

    if (tid < 64) {
      float g = xgv
              + ((part[p][0][tid] + part[p][1][tid]) + (part[p][2][tid] + part[p][3][tid]))
              + ((part[p][4][tid] + part[p][5][tid]) + (part[p][6][tid] + part[p][7][tid]));
      // Parallel activation on all 64 lanes (one exp chain each):
      // gates i,f,o -> sigmoid; gate g -> tanh = 2*sigmoid(2x)-1 (clamped).
      const bool is_g = (gate == 2);
      float xin = is_g ? 2.f * fminf(fmaxf(g, -15.f), 15.f) : g;
      float s = sigmoid_f(xin);
      float act = is_g ? 2.f * s - 1.f : s;
      float vi = __shfl(act, kl);
      float vf = __shfl(act, kl + 16);
      float vg = __shfl(act, kl + 32);
      float vo = __shfl(act, kl + 48);
      if (tid < 16) {
        c = vf * c + vi * vg;
        float h = vo * tanh_f(c);
        const int idx = r * 16 + tid;
        const int sw = idx >> 6, sc = idx & 63;
        u64 pv = (((u64)(unsigned)(t + 1)) << 32) | (u64)__float_as_uint(h);
        // Publish to all 4 replicas (fire-and-forget; acks retire under the
        // next step's poll wait, same as the baseline's single store).
        #pragma unroll
        for (int q = 0; q < NREP; ++q)
          __hip_atomic_store(&g_rep[q][(t + 1) & 1][sw][sc], pv,
                             __ATOMIC_RELAXED, __HIP_MEMORY_SCOPE_AGENT);
        g_h[(t + 1) * 512 + idx] = h;                  // for head (kernel-end flush)
      }
      if (t + 1 < T_STEPS) xgv = xg_at(t + 1);         // off critical path
    }
  }
}

// ---------------- head ----------------
// block j: last[j] = g_h[81+j]  (reshape(T,B,H)[-1] => h_{t=80+j} of batch 255)
// y[l] = relu(last*drop_h[j] . BLW[l] + BLb[l]) * drop_l[j,l]; out = y @ lin_w^T.
// BLb sampled inline per block (256 redundant softplus -- free).
__global__ __launch_bounds__(256) void head_kernel(
    const float* __restrict__ drop_h, const float* __restrict__ drop_l,
    const float* __restrict__ blb_mu, const float* __restrict__ blb_rho,
    const float* __restrict__ eps_blb,
    const float* __restrict__ lin_w, float* __restrict__ out)
{
  const int j = blockIdx.x, tid = threadIdx.x;
  __shared__ float hd[512];
  __shared__ float y[256];

  for (int k = tid; k < 512; k += 256)
    hd[k] = g_h[(81 + j) * 512 + k] * drop_h[j * 512 + k];
  __syncthreads();

  {
    const int l = tid;
    float acc = blb_mu[l] + softplus_f(blb_rho[l]) * eps_blb[l];
    const float* wrow = g_blw + l * 512;
    #pragma unroll 8
    for (int k = 0; k < 512; ++k) acc = fmaf(hd[k], wrow[k], acc);
    acc = fmaxf(acc, 0.f);
    y[l] = acc * drop_l[j * 256 + l];
  }
  __syncthreads();

  if (tid < 10) {
    float acc = 0.f;
    const float* lrow = lin_w + tid * 256;
    #pragma unroll 8
    for (int l = 0; l < 256; ++l) acc = fmaf(y[l], lrow[l], acc);
    out[j * 10 + tid] = acc;
  }
}

// ---------------- launch (2 dispatches) ----------------
extern "C" void kernel_launch(void* const* d_in, const int* in_sizes, int n_in,
                              void* d_out, int out_size, void* d_ws, size_t ws_size,
                              hipStream_t stream) {
  const float* x        = (const float*)d_in[0];
  const float* drop_x   = (const float*)d_in[1];
  const float* drop_h   = (const float*)d_in[2];
  const float* drop_l   = (const float*)d_in[3];
  const float* wih_mu   = (const float*)d_in[4];
  const float* wih_rho  = (const float*)d_in[5];
  const float* eps_wih  = (const float*)d_in[6];
  const float* whh_mu   = (const float*)d_in[7];
  const float* whh_rho  = (const float*)d_in[8];
  const float* eps_whh  = (const float*)d_in[9];
  const float* b_mu     = (const float*)d_in[10];
  const float* b_rho    = (const float*)d_in[11];
  const float* eps_b    = (const float*)d_in[12];
  const float* blw_mu   = (const float*)d_in[13];
  const float* blw_rho  = (const float*)d_in[14];
  const float* eps_blw  = (const float*)d_in[15];
  const float* blb_mu   = (const float*)d_in[16];
  const float* blb_rho  = (const float*)d_in[17];
  const float* eps_blb  = (const float*)d_in[18];
  const float* lin_w    = (const float*)d_in[19];

  lstm_kernel<<<NWG, 512, 0, stream>>>(x, drop_x,
                                       wih_mu, wih_rho, eps_wih,
                                       b_mu, b_rho, eps_b,
                                       whh_mu, whh_rho, eps_whh,
                                       blw_mu, blw_rho, eps_blw);

  head_kernel<<<256, 256, 0, stream>>>(drop_h, drop_l,
                                       blb_mu, blb_rho, eps_blb,
                                       lin_w, (float*)d_out);
}